// Round 14
// baseline (102.558 us; speedup 1.0000x reference)
//
#include <hip/hip_runtime.h>
#include <hip/hip_bf16.h>

#define N_TAGS 128
#define T_LEN  256
#define BSZ    256
#define ROOT_T 126
#define END_T  127
#define LOG16  2.7725887222397811f

typedef _Float16 h2 __attribute__((ext_vector_type(2)));
typedef _Float16 h8 __attribute__((ext_vector_type(8)));
typedef int   i32x4 __attribute__((ext_vector_type(4)));

static __device__ __forceinline__ h2 pkrtz(float a, float b) {
  return __builtin_bit_cast(h2, __builtin_amdgcn_cvt_pkrtz(a, b));
}
static __device__ __forceinline__ float rfl(float x) {
  return __int_as_float(__builtin_amdgcn_readfirstlane(__float_as_int(x)));
}
static __device__ __forceinline__ h2 rdl(h2 v, int k) {
  return __builtin_bit_cast(h2, __builtin_amdgcn_readlane(__builtin_bit_cast(int, v), k));
}
static __device__ __forceinline__ float fdot2(h2 a, h2 b, float c) {
#if __has_builtin(__builtin_amdgcn_fdot2)
  return __builtin_amdgcn_fdot2(a, b, c, false);
#else
  float d;
  asm("v_dot2_f32_f16 %0, %1, %2, %3" : "=v"(d) : "v"(a), "v"(b), "v"(c));
  return d;
#endif
}
static __device__ __forceinline__ float wave_max(float x) {
  #pragma unroll
  for (int d = 1; d < 64; d <<= 1) x = fmaxf(x, __shfl_xor(x, d));
  return x;
}

// LDS-broadcast 128-length dual dot (round 7's proven form).
static __device__ __forceinline__ void dot128(const h2* __restrict__ psv,
                                              const h2 (&EA)[64], const h2 (&EB)[64],
                                              float& s0, float& s1) {
  const h8* pv = (const h8*)psv;
  float a0=0.f,a1=0.f,a2=0.f,a3=0.f, b0=0.f,b1=0.f,b2=0.f,b3=0.f;
  #pragma unroll
  for (int r = 0; r < 16; ++r) {
    const h8 v = pv[r];
    const h2 p0 = __builtin_shufflevector(v, v, 0, 1);
    const h2 p1 = __builtin_shufflevector(v, v, 2, 3);
    const h2 p2 = __builtin_shufflevector(v, v, 4, 5);
    const h2 p3 = __builtin_shufflevector(v, v, 6, 7);
    a0 = fdot2(p0, EA[4*r+0], a0);  a1 = fdot2(p1, EA[4*r+1], a1);
    a2 = fdot2(p2, EA[4*r+2], a2);  a3 = fdot2(p3, EA[4*r+3], a3);
    b0 = fdot2(p0, EB[4*r+0], b0);  b1 = fdot2(p1, EB[4*r+1], b1);
    b2 = fdot2(p2, EB[4*r+2], b2);  b3 = fdot2(p3, EB[4*r+3], b3);
  }
  s0 = (a0 + a1) + (a2 + a3);
  s1 = (b0 + b1) + (b2 + b3);
}

// Register/readlane 128-length dual dot (round 9's proven form).
static __device__ __forceinline__ void dotRL(h2 vp,
                                             const h2 (&EA)[64], const h2 (&EB)[64],
                                             float& s0, float& s1) {
  float a0=0.f,a1=0.f,a2=0.f,a3=0.f, b0=0.f,b1=0.f,b2=0.f,b3=0.f;
  #pragma unroll
  for (int q = 0; q < 64; q += 4) {
    const h2 u0 = rdl(vp, q + 0);
    const h2 u1 = rdl(vp, q + 1);
    const h2 u2 = rdl(vp, q + 2);
    const h2 u3 = rdl(vp, q + 3);
    a0 = fdot2(u0, EA[q + 0], a0);  b0 = fdot2(u0, EB[q + 0], b0);
    a1 = fdot2(u1, EA[q + 1], a1);  b1 = fdot2(u1, EB[q + 1], b1);
    a2 = fdot2(u2, EA[q + 2], a2);  b2 = fdot2(u2, EB[q + 2], b2);
    a3 = fdot2(u3, EA[q + 3], a3);  b3 = fdot2(u3, EB[q + 3], b3);
  }
  s0 = (a0 + a1) + (a2 + a3);
  s1 = (b0 + b1) + (b2 + b3);
}

// One block per batch, 128 threads = 2 waves, no barriers in the main loops.
// EXP-DOMAIN recurrence: p = exp(fv - M) maintained directly; the serial
// chain per step is dot -> mul -> readfirstlane -> v_rcp -> 2 mul -> pack.
// No log/exp on the chain; M accumulates off-chain (L += log(t0)+log16).
// Wave 0 (fwd): LDS-b128-broadcast dot. Wave 1 (bwd): readlane dot
// (side effect: zero DS contention between the waves).
__global__ void
__attribute__((amdgpu_flat_work_group_size(128, 128), amdgpu_waves_per_eu(1, 1)))
crf_fwd_kernel(
    const float* __restrict__ feats,   // [BSZ][T_LEN][N_TAGS]
    const int*   __restrict__ tags,    // [BSZ][T_LEN]
    const int*   __restrict__ mask,    // [BSZ][T_LEN]
    const float* __restrict__ lt,      // [N_TAGS][N_TAGS]
    float*       __restrict__ per_batch)
{
  const int b    = blockIdx.x;
  const int tid  = threadIdx.x;
  const int lane = tid & 63;
  const int wave = tid >> 6;

  __shared__ __align__(16) h2 psF[2][64];
  __shared__ float stage[32 * 129];
  __shared__ float bb[N_TAGS];
  __shared__ float sred[2];

  const float* fb = feats + (size_t)b * T_LEN * N_TAGS;
  const int*   tb = tags  + b * T_LEN;

  // ---- sequence length (prefix mask), per-wave independent ----
  int len;
  {
    const i32x4 mv = ((const i32x4*)(mask + b * T_LEN))[lane];
    int v = mv.x + mv.y + mv.z + mv.w;
    #pragma unroll
    for (int d = 1; d < 64; d <<= 1) v += __shfl_xor(v, d);
    len = __builtin_amdgcn_readfirstlane(v);
  }

  // ---- build f16 register-resident E = exp(lt) ----
  // fwd lane l: EA[q]={E[2q][2l],E[2q+1][2l]}, EB same for col 2l+1.
  // bwd lane l: EA[q]={E[2l][2q],E[2l][2q+1]}, EB same for row 2l+1.
  h2 EA[64], EB[64];
  #pragma unroll
  for (int c = 0; c < 4; ++c) {
    __syncthreads();
    #pragma unroll
    for (int rr = 0; rr < 32; ++rr)
      stage[rr * 129 + tid] = __expf(lt[(c * 32 + rr) * N_TAGS + tid]);
    __syncthreads();
    if (wave == 0) {
      #pragma unroll
      for (int k = 0; k < 16; ++k) {
        h2 ea, eb;
        ea.x = (_Float16)stage[(2*k)   * 129 + 2*lane];
        ea.y = (_Float16)stage[(2*k+1) * 129 + 2*lane];
        eb.x = (_Float16)stage[(2*k)   * 129 + 2*lane + 1];
        eb.y = (_Float16)stage[(2*k+1) * 129 + 2*lane + 1];
        EA[c*16 + k] = ea;
        EB[c*16 + k] = eb;
      }
    } else if ((lane >> 4) == c) {        // rows 2l,2l+1 live in chunk c
      const int r0 = 2 * lane - 32 * c;
      #pragma unroll
      for (int q = 0; q < 64; ++q) {
        h2 ea, eb;
        ea.x = (_Float16)stage[r0       * 129 + 2*q];
        ea.y = (_Float16)stage[r0       * 129 + 2*q + 1];
        eb.x = (_Float16)stage[(r0 + 1) * 129 + 2*q];
        eb.y = (_Float16)stage[(r0 + 1) * 129 + 2*q + 1];
        EA[q] = ea;
        EB[q] = eb;
      }
    }
  }

  float xa0 = 0.f, xa1 = 0.f;            // wave0: final alpha_128 pair

  if (wave == 0) {
    // ===== FORWARD, exp domain: p = exp(fv - Lf), steps t=1..128 =====
    float st0, st1;
    {
      const float2 f0 = ((const float2*)fb)[lane];
      st0 = lt[ROOT_T * N_TAGS + 2*lane]     + f0.x;
      st1 = lt[ROOT_T * N_TAGS + 2*lane + 1] + f0.y;
    }
    float Lf = rfl(st0) + 2.0f;
    h2 p = pkrtz(__expf(st0 - Lf), __expf(st1 - Lf));
    psF[1][lane] = p;
    float2 buf[4];
    buf[1] = ((const float2*)(fb + 1 * N_TAGS))[lane];
    buf[2] = ((const float2*)(fb + 2 * N_TAGS))[lane];
    buf[3] = ((const float2*)(fb + 3 * N_TAGS))[lane];
    buf[0] = ((const float2*)(fb + 4 * N_TAGS))[lane];

    #pragma unroll 4
    for (int t = 1; t <= 128; ++t) {
      const int R = t & 1, W = R ^ 1;
      float s0, s1;
      dot128(psF[R], EA, EB, s0, s1);
      const float2 f = buf[t & 3];                          // feat row t
      buf[t & 3] = ((const float2*)(fb + (t + 4) * N_TAGS))[lane];
      const float ef0 = __expf(f.x), ef1 = __expf(f.y);     // off-chain
      const float t0 = s0 * ef0, t1 = s1 * ef1;
      const bool act = (t < len);
      const float r0 = rfl(t0);
      const float kk = __builtin_amdgcn_rcpf(r0) * 0.0625f;
      const h2 pn = pkrtz(t0 * kk, t1 * kk);
      p = act ? pn : p;
      Lf += act ? (__logf(r0) + LOG16) : 0.0f;              // off-chain
      psF[W][lane] = p;
    }
    xa0 = Lf + __logf((float)p.x);
    xa1 = Lf + __logf((float)p.y);
  } else {
    // ===== BACKWARD, exp domain: u = exp(beta - Lb); r = u*exp(feat) =====
    // step k uses feat row 255-k in its dot; active iff 256-len <= k <= 126.
    float st0 = lt[(2*lane)     * N_TAGS + END_T];
    float st1 = lt[(2*lane + 1) * N_TAGS + END_T];
    float Lb = rfl(st0) + 2.0f;
    h2 u = pkrtz(__expf(st0 - Lb), __expf(st1 - Lb));
    const float2 fw = ((const float2*)(fb + 255 * N_TAGS))[lane];
    h2 efh = pkrtz(__expf(fw.x), __expf(fw.y));
    h2 r = u * efh;                                         // v_pk_mul_f16
    float2 buf[4];
    buf[0] = ((const float2*)(fb + 254 * N_TAGS))[lane];
    buf[1] = ((const float2*)(fb + 253 * N_TAGS))[lane];
    buf[2] = ((const float2*)(fb + 252 * N_TAGS))[lane];
    buf[3] = ((const float2*)(fb + 251 * N_TAGS))[lane];

    const int kmin = 256 - len;
    #pragma unroll 4
    for (int k = 0; k <= 127; ++k) {
      float s0, s1;
      dotRL(r, EA, EB, s0, s1);
      const bool act = (k >= kmin) && (k <= 126);
      const float r0 = rfl(s0);
      const float kk = __builtin_amdgcn_rcpf(r0) * 0.0625f;
      const h2 un = pkrtz(s0 * kk, s1 * kk);
      u = act ? un : u;
      Lb += act ? (__logf(r0) + LOG16) : 0.0f;              // off-chain
      const float2 w2 = buf[k & 3];                         // feat row 254-k
      buf[k & 3] = ((const float2*)(fb + (250 - k) * N_TAGS))[lane];
      efh = pkrtz(__expf(w2.x), __expf(w2.y));              // off-chain
      r = u * efh;
    }
    bb[2*lane]     = Lb + __logf((float)u.x);               // beta_128
    bb[2*lane + 1] = Lb + __logf((float)u.y);
  }
  __syncthreads();

  // ---- gold-path score: 2 timesteps per thread ----
  float c = 0.f;
  #pragma unroll
  for (int q = 0; q < 2; ++q) {
    const int t  = tid + q * N_TAGS;
    const int tg = tb[t];
    if (t == 0)                           c += lt[ROOT_T * N_TAGS + tg];
    if (t >= 1 && t < len)                c += lt[tb[t - 1] * N_TAGS + tg];
    if (t < len && t <= T_LEN - 2)        c += fb[t * N_TAGS + tg];
    if (t == len - 1)                     c += lt[tg * N_TAGS + END_T];
    if (t == T_LEN - 1 && len == T_LEN)   c += fb[t * N_TAGS + tg];
  }
  #pragma unroll
  for (int d = 1; d < 64; d <<= 1) c += __shfl_xor(c, d);
  if (lane == 0) sred[wave] = c;

  // ---- partition: logsumexp(alpha_128 + beta_128), wave 0 ----
  float part = 0.f;
  if (wave == 0) {
    const float x0 = xa0 + bb[2*lane];
    const float x1 = xa1 + bb[2*lane + 1];
    const float mw = wave_max(fmaxf(x0, x1));
    float e = __expf(x0 - mw) + __expf(x1 - mw);
    #pragma unroll
    for (int d = 1; d < 64; d <<= 1) e += __shfl_xor(e, d);
    part = mw + __logf(e);
  }
  __syncthreads();

  if (tid == 0) per_batch[b] = part - (sred[0] + sred[1]);
}

// Deterministic final reduction: mean over 256 per-batch values.
__global__ __launch_bounds__(256) void crf_reduce_kernel(
    const float* __restrict__ per_batch, float* __restrict__ out)
{
  const int tid = threadIdx.x;
  float v = per_batch[tid] * (1.0f / BSZ);
  #pragma unroll
  for (int d = 1; d < 64; d <<= 1) v += __shfl_xor(v, d);
  __shared__ float r[4];
  if ((tid & 63) == 0) r[tid >> 6] = v;
  __syncthreads();
  if (tid == 0) out[0] = r[0] + r[1] + r[2] + r[3];
}

extern "C" void kernel_launch(void* const* d_in, const int* in_sizes, int n_in,
                              void* d_out, int out_size, void* d_ws, size_t ws_size,
                              hipStream_t stream) {
  (void)in_sizes; (void)n_in; (void)out_size; (void)ws_size;
  const float* feats = (const float*)d_in[0];
  const int*   tags  = (const int*)d_in[1];
  const int*   mask  = (const int*)d_in[2];
  const float* lt    = (const float*)d_in[3];
  float* per_batch = (float*)d_ws;   // 256 floats of scratch

  crf_fwd_kernel<<<BSZ, 128, 0, stream>>>(feats, tags, mask, lt, per_batch);
  crf_reduce_kernel<<<1, 256, 0, stream>>>(per_batch, (float*)d_out);
}

// Round 15
// 66.980 us; speedup vs baseline: 1.5312x; 1.5312x over previous
//
#include <hip/hip_runtime.h>
#include <hip/hip_bf16.h>

#define N_TAGS 128
#define T_LEN  256
#define BSZ    256
#define ROOT_T 126
#define END_T  127

typedef _Float16 h2 __attribute__((ext_vector_type(2)));
typedef _Float16 h8 __attribute__((ext_vector_type(8)));
typedef int   i32x4 __attribute__((ext_vector_type(4)));

static __device__ __forceinline__ float fdot2(h2 a, h2 b, float c) {
#if __has_builtin(__builtin_amdgcn_fdot2)
  return __builtin_amdgcn_fdot2(a, b, c, false);
#else
  float d;
  asm("v_dot2_f32_f16 %0, %1, %2, %3" : "=v"(d) : "v"(a), "v"(b), "v"(c));
  return d;
#endif
}

// Block barrier draining ONLY lgkm (DS ops). Global prefetch loads ride
// across it (unlike __syncthreads, which drains vmcnt(0) and serializes the
// feat pipeline -- the round-3 pathology). sched_barrier pins ordering
// (guide rule #18).
static __device__ __forceinline__ void syncLgkm() {
  __builtin_amdgcn_sched_barrier(0);
  asm volatile("s_waitcnt lgkmcnt(0)" ::: "memory");
  __builtin_amdgcn_s_barrier();
  asm volatile("" ::: "memory");
  __builtin_amdgcn_sched_barrier(0);
}

// 128-MAC dot: full p (128 f16 in LDS, 16 wave-uniform b128 broadcasts)
// against this lane's E slice (64 h2 = one column/row). 4 accumulator chains.
static __device__ __forceinline__ float dot64(const _Float16* __restrict__ pp,
                                              const h2 (&E2)[64]) {
  const h8* pv = (const h8*)pp;
  float a0 = 0.f, a1 = 0.f, a2 = 0.f, a3 = 0.f;
  #pragma unroll
  for (int r = 0; r < 16; ++r) {
    const h8 v = pv[r];
    const h2 p0 = __builtin_shufflevector(v, v, 0, 1);
    const h2 p1 = __builtin_shufflevector(v, v, 2, 3);
    const h2 p2 = __builtin_shufflevector(v, v, 4, 5);
    const h2 p3 = __builtin_shufflevector(v, v, 6, 7);
    a0 = fdot2(p0, E2[4*r+0], a0);
    a1 = fdot2(p1, E2[4*r+1], a1);
    a2 = fdot2(p2, E2[4*r+2], a2);
    a3 = fdot2(p3, E2[4*r+3], a3);
  }
  return (a0 + a1) + (a2 + a3);
}

// One block per batch, 256 threads = 4 waves.
// Waves 0-1: forward  -- lane owns ONE column j=tid   (64 fdot2/step).
// Waves 2-3: backward -- lane owns ONE row    j=tid-128.
// One lgkm-only barrier per step exchanges the 128-wide p vector (f16 in LDS)
// and the block-uniform stale normalizer M (1-step-old state[0], +8 headroom:
// p <= e^3 in f16; underflow -> exact 0; blocked -inf lanes stay exact).
__global__ void
__attribute__((amdgpu_flat_work_group_size(256, 256), amdgpu_waves_per_eu(1, 1)))
crf_fwd_kernel(
    const float* __restrict__ feats,   // [BSZ][T_LEN][N_TAGS]
    const int*   __restrict__ tags,    // [BSZ][T_LEN]
    const int*   __restrict__ mask,    // [BSZ][T_LEN]
    const float* __restrict__ lt,      // [N_TAGS][N_TAGS]
    float*       __restrict__ per_batch)
{
  const int b    = blockIdx.x;
  const int tid  = threadIdx.x;
  const int lane = tid & 63;
  const int wave = tid >> 6;
  const bool isF = (wave < 2);
  const int  j   = tid & 127;          // fwd: column; bwd: row

  __shared__ __align__(16) _Float16 pF[2][N_TAGS];
  __shared__ __align__(16) _Float16 pB[2][N_TAGS];
  __shared__ float MF[2], MB[2];
  __shared__ float stage[32 * 129];
  __shared__ float bbs[N_TAGS];
  __shared__ float sred[4];
  __shared__ float red[4];

  const float* fb = feats + (size_t)b * T_LEN * N_TAGS;
  const int*   tb = tags  + b * T_LEN;

  // ---- sequence length (prefix mask), per-wave independent ----
  int len;
  {
    const i32x4 mv = ((const i32x4*)(mask + b * T_LEN))[lane];
    int v = mv.x + mv.y + mv.z + mv.w;
    #pragma unroll
    for (int d = 1; d < 64; d <<= 1) v += __shfl_xor(v, d);
    len = __builtin_amdgcn_readfirstlane(v);
  }

  // ---- f16 register slice of E = exp(lt): one column (fwd) / row (bwd) ----
  // fwd: E2[q] = {E[2q][j], E[2q+1][j]};  bwd: E2[q] = {E[j][2q], E[j][2q+1]}.
  h2 E2[64];
  #pragma unroll
  for (int c = 0; c < 4; ++c) {
    __syncthreads();
    #pragma unroll
    for (int k = 0; k < 16; ++k) {       // 256 threads stage 32 rows
      const int rr = 2 * k + (tid >> 7);
      stage[rr * 129 + (tid & 127)] = __expf(lt[(c * 32 + rr) * N_TAGS + (tid & 127)]);
    }
    __syncthreads();
    if (isF) {
      #pragma unroll
      for (int k = 0; k < 16; ++k) {
        h2 e;
        e.x = (_Float16)stage[(2*k)   * 129 + j];
        e.y = (_Float16)stage[(2*k+1) * 129 + j];
        E2[c*16 + k] = e;
      }
    } else if ((j >> 5) == c) {          // my row lives in this chunk
      const int r0 = j & 31;
      #pragma unroll
      for (int q = 0; q < 64; ++q) {
        h2 e;
        e.x = (_Float16)stage[r0 * 129 + 2*q];
        e.y = (_Float16)stage[r0 * 129 + 2*q + 1];
        E2[q] = e;
      }
    }
  }

  float st, C;
  float buf[4];

  if (isF) {
    // ===== FORWARD: steps t=1..128 (active iff t<len) =====
    st = lt[ROOT_T * N_TAGS + j] + fb[j];
    const float m0 = lt[ROOT_T * N_TAGS] + fb[0];    // st_0[0], uniform loads
    C = m0 + 8.0f;
    pF[1][j] = (_Float16)__expf(st - C);
    if (tid == 0) MF[1] = m0;
    buf[1] = fb[1 * N_TAGS + j];
    buf[2] = fb[2 * N_TAGS + j];
    buf[3] = fb[3 * N_TAGS + j];
    buf[0] = fb[4 * N_TAGS + j];

    #pragma unroll 4
    for (int t = 1; t <= 128; ++t) {
      const int cur = t & 1, nxt = cur ^ 1;
      syncLgkm();                              // p/M from prev step visible
      const float Mp = MF[cur];                // st_{t-1}[0]
      const float s = dot64(pF[cur], E2);
      const float f = buf[t & 3];              // feat row t (mine: col j)
      buf[t & 3] = fb[(t + 4) * N_TAGS + j];
      const float stn = C + __logf(s) + f;
      const bool act = (t < len);
      st = act ? stn : st;
      const float Cn = Mp + 8.0f;
      pF[nxt][j] = (_Float16)__expf(st - Cn);
      if (tid == 0) MF[nxt] = st;
      C = Cn;
    }
    // st = alpha_128[j]
  } else {
    // ===== BACKWARD: step k uses f[255-k] in-flight; active iff
    //       256-len <= k <= 126; ends at beta_128 =====
    st = lt[j * N_TAGS + END_T];               // beta_{len-1}[j]
    const float m0 = lt[END_T] + fb[255 * N_TAGS];   // y_0[0] = lt[0][END]+f255[0]
    const float y0 = st + fb[255 * N_TAGS + j];
    C = m0 + 8.0f;
    pB[0][j] = (_Float16)__expf(y0 - C);
    if (tid == 128) MB[0] = m0;
    buf[0] = fb[254 * N_TAGS + j];
    buf[1] = fb[253 * N_TAGS + j];
    buf[2] = fb[252 * N_TAGS + j];
    buf[3] = fb[251 * N_TAGS + j];

    const int kmin = 256 - len;
    #pragma unroll 4
    for (int k = 0; k <= 127; ++k) {
      const int cur = k & 1, nxt = cur ^ 1;
      syncLgkm();
      const float Mp = MB[cur];                // y_{k-1}[0]
      const float s = dot64(pB[cur], E2);
      const float stn = C + __logf(s);
      const bool act = (k >= kmin) && (k <= 126);
      st = act ? stn : st;
      const float w = buf[k & 3];              // f[254-k] (mine: row j)
      buf[k & 3] = fb[(250 - k) * N_TAGS + j];
      const float y = st + w;
      const float Cn = Mp + 8.0f;
      pB[nxt][j] = (_Float16)__expf(y - Cn);
      if (tid == 128) MB[nxt] = y;
      C = Cn;
    }
    // st = beta_128[j]
    bbs[j] = st;
  }
  __syncthreads();

  // ---- gold-path score: ONE timestep per thread (256 threads) ----
  float c = 0.f;
  {
    const int t  = tid;
    const int tg = tb[t];
    if (t == 0)                           c += lt[ROOT_T * N_TAGS + tg];
    if (t >= 1 && t < len)                c += lt[tb[t - 1] * N_TAGS + tg];
    if (t < len && t <= T_LEN - 2)        c += fb[t * N_TAGS + tg];
    if (t == len - 1)                     c += lt[tg * N_TAGS + END_T];
    if (t == T_LEN - 1 && len == T_LEN)   c += fb[t * N_TAGS + tg];
  }
  #pragma unroll
  for (int d = 1; d < 64; d <<= 1) c += __shfl_xor(c, d);
  if (lane == 0) sred[wave] = c;

  // ---- partition: logsumexp(alpha_128 + beta_128) on waves 0-1 ----
  float x = 0.f;
  if (isF) {
    x = st + bbs[j];
    float mw = x;
    #pragma unroll
    for (int d = 1; d < 64; d <<= 1) mw = fmaxf(mw, __shfl_xor(mw, d));
    if (lane == 0) red[wave] = mw;
  }
  __syncthreads();
  if (isF) {
    const float M = fmaxf(red[0], red[1]);
    float e = __expf(x - M);
    #pragma unroll
    for (int d = 1; d < 64; d <<= 1) e += __shfl_xor(e, d);
    if (lane == 0) red[2 + wave] = e;
  }
  __syncthreads();

  if (tid == 0) {
    const float M         = fmaxf(red[0], red[1]);
    const float partition = M + __logf(red[2] + red[3]);
    per_batch[b] = partition - (sred[0] + sred[1] + sred[2] + sred[3]);
  }
}

// Deterministic final reduction: mean over 256 per-batch values.
__global__ __launch_bounds__(256) void crf_reduce_kernel(
    const float* __restrict__ per_batch, float* __restrict__ out)
{
  const int tid = threadIdx.x;
  float v = per_batch[tid] * (1.0f / BSZ);
  #pragma unroll
  for (int d = 1; d < 64; d <<= 1) v += __shfl_xor(v, d);
  __shared__ float r[4];
  if ((tid & 63) == 0) r[tid >> 6] = v;
  __syncthreads();
  if (tid == 0) out[0] = r[0] + r[1] + r[2] + r[3];
}

extern "C" void kernel_launch(void* const* d_in, const int* in_sizes, int n_in,
                              void* d_out, int out_size, void* d_ws, size_t ws_size,
                              hipStream_t stream) {
  (void)in_sizes; (void)n_in; (void)out_size; (void)ws_size;
  const float* feats = (const float*)d_in[0];
  const int*   tags  = (const int*)d_in[1];
  const int*   mask  = (const int*)d_in[2];
  const float* lt    = (const float*)d_in[3];
  float* per_batch = (float*)d_ws;   // 256 floats of scratch

  crf_fwd_kernel<<<BSZ, 256, 0, stream>>>(feats, tags, mask, lt, per_batch);
  crf_reduce_kernel<<<1, 256, 0, stream>>>(per_batch, (float*)d_out);
}

// Round 16
// 66.241 us; speedup vs baseline: 1.5482x; 1.0112x over previous
//
#include <hip/hip_runtime.h>
#include <hip/hip_bf16.h>

#define N_TAGS 128
#define T_LEN  256
#define BSZ    256
#define ROOT_T 126
#define END_T  127

typedef _Float16 h2 __attribute__((ext_vector_type(2)));
typedef _Float16 h8 __attribute__((ext_vector_type(8)));
typedef int   i32x4 __attribute__((ext_vector_type(4)));

static __device__ __forceinline__ float fdot2(h2 a, h2 b, float c) {
#if __has_builtin(__builtin_amdgcn_fdot2)
  return __builtin_amdgcn_fdot2(a, b, c, false);
#else
  float d;
  asm("v_dot2_f32_f16 %0, %1, %2, %3" : "=v"(d) : "v"(a), "v"(b), "v"(c));
  return d;
#endif
}

// Block barrier draining ONLY lgkm (DS ops). Global prefetch loads ride
// across it (unlike __syncthreads, which drains vmcnt(0) and serializes the
// feat pipeline). sched_barrier pins ordering (guide rule #18).
static __device__ __forceinline__ void syncLgkm() {
  __builtin_amdgcn_sched_barrier(0);
  asm volatile("s_waitcnt lgkmcnt(0)" ::: "memory");
  __builtin_amdgcn_s_barrier();
  asm volatile("" ::: "memory");
  __builtin_amdgcn_sched_barrier(0);
}

// 128-MAC dot: full p (128 f16 in LDS, 16 wave-uniform b128 broadcasts)
// against this lane's E slice (64 h2 = one column/row). 4 accumulator chains.
static __device__ __forceinline__ float dot64(const _Float16* __restrict__ pp,
                                              const h2 (&E2)[64]) {
  const h8* pv = (const h8*)pp;
  float a0 = 0.f, a1 = 0.f, a2 = 0.f, a3 = 0.f;
  #pragma unroll
  for (int r = 0; r < 16; ++r) {
    const h8 v = pv[r];
    const h2 p0 = __builtin_shufflevector(v, v, 0, 1);
    const h2 p1 = __builtin_shufflevector(v, v, 2, 3);
    const h2 p2 = __builtin_shufflevector(v, v, 4, 5);
    const h2 p3 = __builtin_shufflevector(v, v, 6, 7);
    a0 = fdot2(p0, E2[4*r+0], a0);
    a1 = fdot2(p1, E2[4*r+1], a1);
    a2 = fdot2(p2, E2[4*r+2], a2);
    a3 = fdot2(p3, E2[4*r+3], a3);
  }
  return (a0 + a1) + (a2 + a3);
}

// One block per batch, 256 threads = 4 waves (round-15 structure).
// Waves 0-1: forward  -- lane owns ONE column j=tid   (64 fdot2/step).
// Waves 2-3: backward -- lane owns ONE row    j=tid-128.
// One lgkm-only barrier per step exchanges the 128-wide p vector (f16 LDS)
// and the block-uniform stale normalizer M (1-step-old state[0], +8 headroom).
// NEW vs round 15: single-pass f16 E-table prologue (1 barrier instead of 8,
// no f32 stage) -- the loop is byte-identical to the passing round-15 kernel.
__global__ void
__attribute__((amdgpu_flat_work_group_size(256, 256), amdgpu_waves_per_eu(1, 1)))
crf_fwd_kernel(
    const float* __restrict__ feats,   // [BSZ][T_LEN][N_TAGS]
    const int*   __restrict__ tags,    // [BSZ][T_LEN]
    const int*   __restrict__ mask,    // [BSZ][T_LEN]
    const float* __restrict__ lt,      // [N_TAGS][N_TAGS]
    float*       __restrict__ per_batch)
{
  const int b    = blockIdx.x;
  const int tid  = threadIdx.x;
  const int lane = tid & 63;
  const int wave = tid >> 6;
  const bool isF = (wave < 2);
  const int  j   = tid & 127;          // fwd: column; bwd: row

  __shared__ __align__(16) _Float16 Etab[N_TAGS][130];  // E=exp(lt), f16, pad 2
  __shared__ __align__(16) _Float16 pF[2][N_TAGS];
  __shared__ __align__(16) _Float16 pB[2][N_TAGS];
  __shared__ float MF[2], MB[2];
  __shared__ float bbs[N_TAGS];
  __shared__ float sred[4];
  __shared__ float red[4];

  const float* fb = feats + (size_t)b * T_LEN * N_TAGS;
  const int*   tb = tags  + b * T_LEN;

  // ---- sequence length (prefix mask), per-wave independent ----
  int len;
  {
    const i32x4 mv = ((const i32x4*)(mask + b * T_LEN))[lane];
    int v = mv.x + mv.y + mv.z + mv.w;
    #pragma unroll
    for (int d = 1; d < 64; d <<= 1) v += __shfl_xor(v, d);
    len = __builtin_amdgcn_readfirstlane(v);
  }

  // ---- single-pass f16 E-table: Etab[r][c] = exp(lt[r][c]) ----
  {
    const int c = tid & 127;
    #pragma unroll 8
    for (int i = 0; i < 64; ++i) {
      const int r = 2 * i + (tid >> 7);
      Etab[r][c] = (_Float16)__expf(lt[r * N_TAGS + c]);   // coalesced load
    }
  }
  __syncthreads();

  // ---- register slice: fwd E2[q]={E[2q][j],E[2q+1][j]}; bwd row j ----
  h2 E2[64];
  if (isF) {
    #pragma unroll
    for (int q = 0; q < 64; ++q) {
      h2 e;
      e.x = Etab[2*q][j];
      e.y = Etab[2*q+1][j];
      E2[q] = e;
    }
  } else {
    const h2* rowp = (const h2*)(&Etab[j][0]);   // 260B row stride: 4B aligned
    #pragma unroll
    for (int q = 0; q < 64; ++q) E2[q] = rowp[q];
  }

  float st, C;
  float buf[4];

  if (isF) {
    // ===== FORWARD: steps t=1..128 (active iff t<len) =====
    st = lt[ROOT_T * N_TAGS + j] + fb[j];
    const float m0 = lt[ROOT_T * N_TAGS] + fb[0];    // st_0[0], uniform loads
    C = m0 + 8.0f;
    pF[1][j] = (_Float16)__expf(st - C);
    if (tid == 0) MF[1] = m0;
    buf[1] = fb[1 * N_TAGS + j];
    buf[2] = fb[2 * N_TAGS + j];
    buf[3] = fb[3 * N_TAGS + j];
    buf[0] = fb[4 * N_TAGS + j];

    #pragma unroll 4
    for (int t = 1; t <= 128; ++t) {
      const int cur = t & 1, nxt = cur ^ 1;
      syncLgkm();                              // p/M from prev step visible
      const float Mp = MF[cur];                // st_{t-1}[0]
      const float s = dot64(pF[cur], E2);
      const float f = buf[t & 3];              // feat row t (mine: col j)
      buf[t & 3] = fb[(t + 4) * N_TAGS + j];
      const float stn = C + __logf(s) + f;
      const bool act = (t < len);
      st = act ? stn : st;
      const float Cn = Mp + 8.0f;
      pF[nxt][j] = (_Float16)__expf(st - Cn);
      if (tid == 0) MF[nxt] = st;
      C = Cn;
    }
    // st = alpha_128[j]
  } else {
    // ===== BACKWARD: step k uses f[255-k] in-flight; active iff
    //       256-len <= k <= 126; ends at beta_128 =====
    st = lt[j * N_TAGS + END_T];               // beta_{len-1}[j]
    const float m0 = lt[END_T] + fb[255 * N_TAGS];   // y_0[0]
    const float y0 = st + fb[255 * N_TAGS + j];
    C = m0 + 8.0f;
    pB[0][j] = (_Float16)__expf(y0 - C);
    if (tid == 128) MB[0] = m0;
    buf[0] = fb[254 * N_TAGS + j];
    buf[1] = fb[253 * N_TAGS + j];
    buf[2] = fb[252 * N_TAGS + j];
    buf[3] = fb[251 * N_TAGS + j];

    const int kmin = 256 - len;
    #pragma unroll 4
    for (int k = 0; k <= 127; ++k) {
      const int cur = k & 1, nxt = cur ^ 1;
      syncLgkm();
      const float Mp = MB[cur];                // y_{k-1}[0]
      const float s = dot64(pB[cur], E2);
      const float stn = C + __logf(s);
      const bool act = (k >= kmin) && (k <= 126);
      st = act ? stn : st;
      const float w = buf[k & 3];              // f[254-k] (mine: row j)
      buf[k & 3] = fb[(250 - k) * N_TAGS + j];
      const float y = st + w;
      const float Cn = Mp + 8.0f;
      pB[nxt][j] = (_Float16)__expf(y - Cn);
      if (tid == 128) MB[nxt] = y;
      C = Cn;
    }
    // st = beta_128[j]
    bbs[j] = st;
  }
  __syncthreads();

  // ---- gold-path score: ONE timestep per thread (256 threads) ----
  float c = 0.f;
  {
    const int t  = tid;
    const int tg = tb[t];
    if (t == 0)                           c += lt[ROOT_T * N_TAGS + tg];
    if (t >= 1 && t < len)                c += lt[tb[t - 1] * N_TAGS + tg];
    if (t < len && t <= T_LEN - 2)        c += fb[t * N_TAGS + tg];
    if (t == len - 1)                     c += lt[tg * N_TAGS + END_T];
    if (t == T_LEN - 1 && len == T_LEN)   c += fb[t * N_TAGS + tg];
  }
  #pragma unroll
  for (int d = 1; d < 64; d <<= 1) c += __shfl_xor(c, d);
  if (lane == 0) sred[wave] = c;

  // ---- partition: logsumexp(alpha_128 + beta_128) on waves 0-1 ----
  float x = 0.f;
  if (isF) {
    x = st + bbs[j];
    float mw = x;
    #pragma unroll
    for (int d = 1; d < 64; d <<= 1) mw = fmaxf(mw, __shfl_xor(mw, d));
    if (lane == 0) red[wave] = mw;
  }
  __syncthreads();
  if (isF) {
    const float M = fmaxf(red[0], red[1]);
    float e = __expf(x - M);
    #pragma unroll
    for (int d = 1; d < 64; d <<= 1) e += __shfl_xor(e, d);
    if (lane == 0) red[2 + wave] = e;
  }
  __syncthreads();

  if (tid == 0) {
    const float M         = fmaxf(red[0], red[1]);
    const float partition = M + __logf(red[2] + red[3]);
    per_batch[b] = partition - (sred[0] + sred[1] + sred[2] + sred[3]);
  }
}

// Deterministic final reduction: mean over 256 per-batch values.
__global__ __launch_bounds__(256) void crf_reduce_kernel(
    const float* __restrict__ per_batch, float* __restrict__ out)
{
  const int tid = threadIdx.x;
  float v = per_batch[tid] * (1.0f / BSZ);
  #pragma unroll
  for (int d = 1; d < 64; d <<= 1) v += __shfl_xor(v, d);
  __shared__ float r[4];
  if ((tid & 63) == 0) r[tid >> 6] = v;
  __syncthreads();
  if (tid == 0) out[0] = r[0] + r[1] + r[2] + r[3];
}

extern "C" void kernel_launch(void* const* d_in, const int* in_sizes, int n_in,
                              void* d_out, int out_size, void* d_ws, size_t ws_size,
                              hipStream_t stream) {
  (void)in_sizes; (void)n_in; (void)out_size; (void)ws_size;
  const float* feats = (const float*)d_in[0];
  const int*   tags  = (const int*)d_in[1];
  const int*   mask  = (const int*)d_in[2];
  const float* lt    = (const float*)d_in[3];
  float* per_batch = (float*)d_ws;   // 256 floats of scratch

  crf_fwd_kernel<<<BSZ, 256, 0, stream>>>(feats, tags, mask, lt, per_batch);
  crf_reduce_kernel<<<1, 256, 0, stream>>>(per_batch, (float*)d_out);
}